// Round 3
// baseline (263.742 us; speedup 1.0000x reference)
//
#include <hip/hip_runtime.h>
#include <math.h>

#define T_TOTAL 262144
#define HIDN 20
#define IND 9
#define CHUNK 256
#define WARM 96
#define MAXST (WARM + CHUNK + 1)   // 353 iterations per chunk
#define NBLK (T_TOTAL / CHUNK)     // 1024 blocks

// Opaque register pin: prevents the compiler from sinking weight loads into
// the loop (round-2 VGPR=132 showed it re-loaded weights every iteration,
// and __syncthreads' vmcnt(0) then serialized on them).
#define KEEP(x) asm volatile("" : "+v"(x))

__device__ __forceinline__ float fexp(float x) {
    return __builtin_amdgcn_exp2f(x * 1.44269504088896340736f);
}
__device__ __forceinline__ float sigf(float x) {
    return __builtin_amdgcn_rcpf(1.0f + fexp(-x));
}
__device__ __forceinline__ float tanhfst(float x) {
    return 1.0f - 2.0f * __builtin_amdgcn_rcpf(1.0f + fexp(2.0f * x));
}

__device__ __forceinline__ void loadx(float xv[IND], const float* xr) {
    float4 xa = *(const float4*)xr;
    float4 xb = *(const float4*)(xr + 4);
    xv[0]=xa.x; xv[1]=xa.y; xv[2]=xa.z; xv[3]=xa.w;
    xv[4]=xb.x; xv[5]=xb.y; xv[6]=xb.z; xv[7]=xb.w;
    xv[8]=xr[8];
}

// 29-term dot with 4 independent accumulators (dep chain ~10 FMA deep).
__device__ __forceinline__ float dot29(const float* wvq, const float* wxq, float bq,
                                       const float* v, const float* xv) {
    float t0 = bq, t1 = 0.f, t2 = 0.f, t3 = 0.f;
    #pragma unroll
    for (int j = 0; j < 20; j += 4) {
        t0 = fmaf(wvq[j+0], v[j+0], t0);
        t1 = fmaf(wvq[j+1], v[j+1], t1);
        t2 = fmaf(wvq[j+2], v[j+2], t2);
        t3 = fmaf(wvq[j+3], v[j+3], t3);
    }
    #pragma unroll
    for (int d = 0; d < 8; d += 4) {
        t0 = fmaf(wxq[d+0], xv[d+0], t0);
        t1 = fmaf(wxq[d+1], xv[d+1], t1);
        t2 = fmaf(wxq[d+2], xv[d+2], t2);
        t3 = fmaf(wxq[d+3], xv[d+3], t3);
    }
    t0 = fmaf(wxq[8], xv[8], t0);
    return (t0 + t1) + (t2 + t3);
}

// Lanes 0-19: layer1 unit k. Lanes 20-39: layer2 W_ih2 half (state owner).
// Lanes 40-59: layer2 W_hh2 half. Layer 2 runs one step behind layer 1.
__global__ __launch_bounds__(64, 1)
void lstm_scan(const float* __restrict__ x,
               const float* __restrict__ w_ih1, const float* __restrict__ w_hh1,
               const float* __restrict__ b1,
               const float* __restrict__ w_ih2, const float* __restrict__ w_hh2,
               const float* __restrict__ b2,
               const float* __restrict__ w_p, const float* __restrict__ b_p,
               float* __restrict__ out)
{
    __shared__ __align__(16) float xbuf[(MAXST + 1) * 12]; // +1 row: prefetch overrun pad
    __shared__ __align__(16) float hcur[128];              // h1@[0..19], h2@[32..51], dump@[64..87]
    __shared__ __align__(16) float h2out[CHUNK * HIDN + 64]; // +64: dump row

    const int lane = threadIdx.x;
    const int blk  = blockIdx.x;
    const int t0   = blk * CHUNK;
    const int start = (t0 >= WARM) ? (t0 - WARM) : 0;
    const int endt  = t0 + CHUNK;
    const int nst   = endt - start + 1;

    // ---- stage x chunk into LDS (stride 12 for aligned b128 reads)
    for (int idx = lane; idx < nst * IND; idx += 64) {
        int stp = idx / IND, d = idx - stp * IND;
        int gt = start + stp; if (gt > T_TOTAL - 1) gt = T_TOTAL - 1;
        xbuf[stp * 12 + d] = x[gt * IND + d];
    }
    if (lane < 64) { hcur[lane] = 0.0f; hcur[64 + lane] = 0.0f; }

    // ---- per-lane weight registers (loaded once, pinned with KEEP)
    float wv[4][HIDN];
    float wx[4][IND];
    float bias[4];
    {
        const int grp = lane / 20;
        const int k   = lane - grp * 20;
        #pragma unroll
        for (int q = 0; q < 4; ++q) {
            const int row = q * HIDN + k;   // PyTorch gate order i,f,g,o
            #pragma unroll
            for (int j = 0; j < HIDN; ++j) {
                float w = 0.0f;
                if (grp == 0)      w = w_hh1[row * HIDN + j];
                else if (grp == 1) w = w_ih2[row * HIDN + j];
                else if (grp == 2) w = w_hh2[row * HIDN + j];
                wv[q][j] = w;
            }
            #pragma unroll
            for (int d = 0; d < IND; ++d)
                wx[q][d] = (grp == 0) ? w_ih1[row * IND + d] : 0.0f;
            bias[q] = (grp == 0) ? b1[row] : ((grp == 1) ? b2[row] : 0.0f);
        }
    }
    #pragma unroll
    for (int q = 0; q < 4; ++q) {
        #pragma unroll
        for (int j = 0; j < HIDN; ++j) KEEP(wv[q][j]);
        #pragma unroll
        for (int d = 0; d < IND; ++d) KEEP(wx[q][d]);
        KEEP(bias[q]);
    }

    const float* vbase = (lane < 40) ? hcur : (hcur + 32);
    const int   hslot  = (lane < 20) ? lane
                       : ((lane < 40) ? 32 + (lane - 20) : 64 + (lane - 40));
    const bool  isl2   = (lane >= 20 && lane < 40);
    const float m2     = isl2 ? 1.0f : 0.0f;
    const int   h2col  = lane - 20;

    __syncthreads();

    float xv[IND];
    loadx(xv, &xbuf[0]);

    float c = 0.0f, h = 0.0f;

    // ---- peeled first step (s == start): commit layer-1 only
    {
        float v[HIDN];
        #pragma unroll
        for (int j = 0; j < HIDN; ++j) v[j] = vbase[j];   // all zeros
        float a[4];
        #pragma unroll
        for (int q = 0; q < 4; ++q) a[q] = dot29(wv[q], wx[q], bias[q], v, xv);
        float gi = sigf(a[0]), gf = sigf(a[1]), gg = tanhfst(a[2]), go = sigf(a[3]);
        float cn = gf * c + gi * gg;
        float hn = go * tanhfst(cn);
        c = (lane < 20) ? cn : 0.0f;
        h = (lane < 20) ? hn : 0.0f;
        hcur[hslot] = h;
        loadx(xv, &xbuf[12]);
        __syncthreads();
    }

    // ---- main loop: s = start+1 .. endt (no commit selects needed)
    for (int s = start + 1; s <= endt; ++s) {
        float v[HIDN];
        {
            const float4* vb4 = (const float4*)vbase;
            float4 q0 = vb4[0], q1 = vb4[1], q2 = vb4[2], q3 = vb4[3], q4 = vb4[4];
            v[0]=q0.x; v[1]=q0.y; v[2]=q0.z; v[3]=q0.w;
            v[4]=q1.x; v[5]=q1.y; v[6]=q1.z; v[7]=q1.w;
            v[8]=q2.x; v[9]=q2.y; v[10]=q2.z; v[11]=q2.w;
            v[12]=q3.x; v[13]=q3.y; v[14]=q3.z; v[15]=q3.w;
            v[16]=q4.x; v[17]=q4.y; v[18]=q4.z; v[19]=q4.w;
        }

        float a[4];
        #pragma unroll
        for (int q = 0; q < 4; ++q) a[q] = dot29(wv[q], wx[q], bias[q], v, xv);

        // layer-2 combine: lane 20+k += lane 40+k (mask-fma, no branch)
        #pragma unroll
        for (int q = 0; q < 4; ++q) {
            float other = __shfl(a[q], (lane + 20) & 63, 64);
            a[q] = fmaf(m2, other, a[q]);
        }

        float gi = sigf(a[0]), gf = sigf(a[1]), gg = tanhfst(a[2]), go = sigf(a[3]);
        c = gf * c + gi * gg;
        h = go * tanhfst(c);

        // branch-free LDS commits (invalid lanes write dump slots)
        hcur[hslot] = h;
        int idx = s - 1 - t0; idx = (idx < 0) ? 0 : idx;
        int h2addr = isl2 ? (idx * HIDN + h2col) : (CHUNK * HIDN + lane);
        h2out[h2addr] = h;

        loadx(xv, &xbuf[(s + 1 - start) * 12]);   // prefetch next row (padded)
        __syncthreads();
    }

    // ---- projection epilogue: out[t] = w_p . h2[t] + b_p
    float wp[HIDN];
    #pragma unroll
    for (int j = 0; j < HIDN; ++j) wp[j] = w_p[j];
    const float bp = b_p[0];
    for (int tt = lane; tt < CHUNK; tt += 64) {
        float acc = bp;
        #pragma unroll
        for (int j = 0; j < HIDN; ++j) acc += wp[j] * h2out[tt * HIDN + j];
        out[t0 + tt] = acc;
    }
}

extern "C" void kernel_launch(void* const* d_in, const int* in_sizes, int n_in,
                              void* d_out, int out_size, void* d_ws, size_t ws_size,
                              hipStream_t stream) {
    const float* x     = (const float*)d_in[0];
    const float* w_ih1 = (const float*)d_in[1];
    const float* w_hh1 = (const float*)d_in[2];
    const float* b1    = (const float*)d_in[3];
    const float* w_ih2 = (const float*)d_in[4];
    const float* w_hh2 = (const float*)d_in[5];
    const float* b2    = (const float*)d_in[6];
    const float* w_p   = (const float*)d_in[7];
    const float* b_p   = (const float*)d_in[8];
    float* out = (float*)d_out;

    lstm_scan<<<NBLK, 64, 0, stream>>>(x, w_ih1, w_hh1, b1,
                                       w_ih2, w_hh2, b2, w_p, b_p, out);
}

// Round 4
// 234.220 us; speedup vs baseline: 1.1260x; 1.1260x over previous
//
#include <hip/hip_runtime.h>
#include <math.h>

#define T_TOTAL 262144
#define HIDN 20
#define IND 9
#define CHUNK 256
#define WARM 96
#define MAXST (WARM + CHUNK + 1)   // 353 iterations per chunk
#define NBLK (T_TOTAL / CHUNK)     // 1024 blocks

typedef float float4v __attribute__((ext_vector_type(4)));

__device__ __forceinline__ float fexp(float x) {
    return __builtin_amdgcn_exp2f(x * 1.44269504088896340736f);
}
__device__ __forceinline__ float sigf(float x) {
    return __builtin_amdgcn_rcpf(1.0f + fexp(-x));
}
__device__ __forceinline__ float tanhfst(float x) {
    return 1.0f - 2.0f * __builtin_amdgcn_rcpf(1.0f + fexp(2.0f * x));
}
__device__ __forceinline__ float hsum4(float4v a) {
    return (a.x + a.y) + (a.z + a.w);
}

// Per-gate weight registers as NAMED float4 SSA values — no arrays, no
// scratch backing possible short of allocator spill (budget pinned by
// amdgpu_waves_per_eu(1,1): 1 wave/EU -> ~512 VGPRs available).
#define DECLW(q) \
    float4v wv##q##0, wv##q##1, wv##q##2, wv##q##3, wv##q##4; \
    float4v wx##q##0, wx##q##1; float wx##q##8; float bq##q;

#define LOADW(q) { \
    const float4v* wr = (const float4v*)(wbase + ((q) * HIDN + krow) * HIDN); \
    wv##q##0 = scale * wr[0]; wv##q##1 = scale * wr[1]; wv##q##2 = scale * wr[2]; \
    wv##q##3 = scale * wr[3]; wv##q##4 = scale * wr[4]; \
    wx##q##0 = (float4v)0.0f; wx##q##1 = (float4v)0.0f; wx##q##8 = 0.0f; \
    if (grp == 0) { \
        const float* r = w_ih1 + ((q) * HIDN + k) * IND; \
        wx##q##0 = (float4v){r[0], r[1], r[2], r[3]}; \
        wx##q##1 = (float4v){r[4], r[5], r[6], r[7]}; \
        wx##q##8 = r[8]; \
    } \
    bq##q = (grp == 0) ? b1[(q) * HIDN + k] : ((grp == 1) ? b2[(q) * HIDN + k] : 0.0f); \
}

// full 29-term gate: 20 h-terms + 9 x-terms + bias
#define GATE(q) ({ \
    float4v s_ = wv##q##0 * v0; \
    s_ += wv##q##1 * v1; s_ += wv##q##2 * v2; \
    s_ += wv##q##3 * v3; s_ += wv##q##4 * v4; \
    s_ += wx##q##0 * xv0; s_ += wx##q##1 * xv1; \
    hsum4(s_) + fmaf(wx##q##8, xv8, bq##q); })

// x-only gate for the peeled first step (h = c = 0)
#define GATEX(q) ({ \
    float4v s_ = wx##q##0 * xv0 + wx##q##1 * xv1; \
    hsum4(s_) + fmaf(wx##q##8, xv8, bq##q); })

// Lanes 0-19: layer1 unit k. Lanes 20-39: layer2 W_ih2 half (state owner).
// Lanes 40-59: layer2 W_hh2 half. Lanes 60-63: zero weights (idle).
__global__ __attribute__((amdgpu_waves_per_eu(1, 1))) __launch_bounds__(64)
void lstm_scan(const float* __restrict__ x,
               const float* __restrict__ w_ih1, const float* __restrict__ w_hh1,
               const float* __restrict__ b1,
               const float* __restrict__ w_ih2, const float* __restrict__ w_hh2,
               const float* __restrict__ b2,
               const float* __restrict__ w_p, const float* __restrict__ b_p,
               float* __restrict__ out)
{
    __shared__ __align__(16) float xbuf[MAXST * 12];   // stride 12 floats = 48B (b128 aligned)
    __shared__ __align__(16) float hcur[64];           // h1@[0..19], h2@[32..51]
    __shared__ __align__(16) float h2out[CHUNK * HIDN];

    const int lane = threadIdx.x;
    const int blk  = blockIdx.x;
    const int t0   = blk * CHUNK;
    const int start = (t0 >= WARM) ? (t0 - WARM) : 0;
    const int endt  = t0 + CHUNK;
    const int nst   = endt - start + 1;

    // ---- stage x chunk into LDS (coalesced; clamp last padded row)
    for (int idx = lane; idx < nst * IND; idx += 64) {
        int stp = idx / IND, d = idx - stp * IND;
        int gt = start + stp; if (gt > T_TOTAL - 1) gt = T_TOTAL - 1;
        xbuf[stp * 12 + d] = x[gt * IND + d];
    }
    hcur[lane] = 0.0f;

    // ---- per-lane weights in named float4 registers
    const int grp  = lane / 20;
    const int k    = lane - grp * 20;
    const int krow = (grp < 3) ? k : 0;
    const float scale = (grp < 3) ? 1.0f : 0.0f;
    const float* wbase = (grp == 1) ? w_ih2 : ((grp == 2) ? w_hh2 : w_hh1);

    DECLW(0) DECLW(1) DECLW(2) DECLW(3)
    LOADW(0) LOADW(1) LOADW(2) LOADW(3)

    const float* vbase = (lane < 40) ? hcur : (hcur + 32);
    const bool  isl2   = (lane >= 20 && lane < 40);
    const float m2     = isl2 ? 1.0f : 0.0f;
    const int   h2col  = lane - 20;
    const int   hslot  = (lane < 20) ? lane : (32 + h2col);
    const int   shsrc  = (lane + 20) & 63;

    __syncthreads();

    float c = 0.0f, h = 0.0f;

    // ---- peeled first step (s == start): h,c are zero -> x-only gates
    {
        const float* xr = &xbuf[0];
        float4v xv0 = *(const float4v*)xr, xv1 = *(const float4v*)(xr + 4);
        float xv8 = xr[8];
        float a0 = GATEX(0), a1 = GATEX(1), a2 = GATEX(2), a3 = GATEX(3);
        float gi = sigf(a0), gf = sigf(a1), gg = tanhfst(a2), go = sigf(a3);
        float cn = gi * gg;       // c was 0
        float hn = go * tanhfst(cn);
        c = (lane < 20) ? cn : 0.0f;
        h = (lane < 20) ? hn : 0.0f;
        if (lane < 40) hcur[hslot] = h;   // layer-2 slots stay 0
        __syncthreads();
    }

    // ---- main loop: s = start+1 .. endt
    for (int s = start + 1; s <= endt; ++s) {
        const float4v* vb4 = (const float4v*)vbase;
        float4v v0 = vb4[0], v1 = vb4[1], v2 = vb4[2], v3 = vb4[3], v4 = vb4[4];

        const float* xr = &xbuf[(s - start) * 12];
        float4v xv0 = *(const float4v*)xr, xv1 = *(const float4v*)(xr + 4);
        float xv8 = xr[8];

        float a0 = GATE(0), a1 = GATE(1), a2 = GATE(2), a3 = GATE(3);

        // layer-2 combine: lane 20+k += lane 40+k (masked fma)
        a0 = fmaf(m2, __shfl(a0, shsrc, 64), a0);
        a1 = fmaf(m2, __shfl(a1, shsrc, 64), a1);
        a2 = fmaf(m2, __shfl(a2, shsrc, 64), a2);
        a3 = fmaf(m2, __shfl(a3, shsrc, 64), a3);

        float gi = sigf(a0), gf = sigf(a1), gg = tanhfst(a2), go = sigf(a3);
        c = fmaf(gf, c, gi * gg);
        h = go * tanhfst(c);

        if (lane < 40) hcur[hslot] = h;                       // 2-way bank alias: free
        if (isl2 && s > t0) h2out[(s - 1 - t0) * HIDN + h2col] = h;

        __syncthreads();
    }

    // ---- projection epilogue: out[t] = w_p . h2[t] + b_p
    {
        const float4v* wp4 = (const float4v*)w_p;
        float4v p0 = wp4[0], p1 = wp4[1], p2 = wp4[2], p3 = wp4[3], p4 = wp4[4];
        const float bp = b_p[0];
        for (int tt = lane; tt < CHUNK; tt += 64) {
            const float4v* hr = (const float4v*)(h2out + tt * HIDN);
            float4v s_ = p0 * hr[0];
            s_ += p1 * hr[1]; s_ += p2 * hr[2]; s_ += p3 * hr[3]; s_ += p4 * hr[4];
            out[t0 + tt] = hsum4(s_) + bp;
        }
    }
}

extern "C" void kernel_launch(void* const* d_in, const int* in_sizes, int n_in,
                              void* d_out, int out_size, void* d_ws, size_t ws_size,
                              hipStream_t stream) {
    const float* x     = (const float*)d_in[0];
    const float* w_ih1 = (const float*)d_in[1];
    const float* w_hh1 = (const float*)d_in[2];
    const float* b1    = (const float*)d_in[3];
    const float* w_ih2 = (const float*)d_in[4];
    const float* w_hh2 = (const float*)d_in[5];
    const float* b2    = (const float*)d_in[6];
    const float* w_p   = (const float*)d_in[7];
    const float* b_p   = (const float*)d_in[8];
    float* out = (float*)d_out;

    lstm_scan<<<NBLK, 64, 0, stream>>>(x, w_ih1, w_hh1, b1,
                                       w_ih2, w_hh2, b2, w_p, b_p, out);
}